// Round 9
// baseline (268.773 us; speedup 1.0000x reference)
//
#include <hip/hip_runtime.h>
#include <stdint.h>

#define NH 12
#define HD 64
#define NB 4
#define SEQ 1024
#define CDIM 768
#define MTOT (NB*SEQ)
#define MC   (MTOT*CDIM)      /* 3145728 */
#define LC   (SEQ*CDIM)       /* 786432  */
#define WSZ  (CDIM*CDIM)      /* 589824  */
#define LST  104              /* attn P-buffer LDS row stride (shorts) */
#define EST  136              /* epilogue LDS row stride (shorts) */
#define L2E  1.44269504f

typedef __attribute__((ext_vector_type(4))) float f32x4;
typedef __attribute__((ext_vector_type(8))) __bf16 bf16x8;
typedef __attribute__((ext_vector_type(8))) short short8;
typedef __attribute__((ext_vector_type(4))) unsigned short ushort4v;
typedef unsigned short u16;

static __device__ __forceinline__ f32x4 mfma16(short8 a, short8 b, f32x4 c) {
  return __builtin_amdgcn_mfma_f32_16x16x32_bf16(
      __builtin_bit_cast(bf16x8, a), __builtin_bit_cast(bf16x8, b), c, 0, 0, 0);
}
static __device__ __forceinline__ u16 f2bf(float f) {
  unsigned u = __float_as_uint(f);
  u += 0x7FFFu + ((u >> 16) & 1u);
  return (u16)(u >> 16);
}
static __device__ __forceinline__ float bf2f(u16 h) {
  return __uint_as_float(((unsigned)h) << 16);
}
static __device__ __forceinline__ void lds_load16(const void* g, void* l) {
  __builtin_amdgcn_global_load_lds(
      (const __attribute__((address_space(1))) void*)g,
      (__attribute__((address_space(3))) void*)l, 16, 0, 0);
}

// ---- fused prep: Xq/Xk/Xv bf16 tokens + all weights/bias -> bf16 ----
#define PREP_BLKS (MC / 4 / 256)
#define CONV_N4   ((4 * WSZ + CDIM) / 4)
#define CONV_BLKS ((CONV_N4 + 255) / 256)
__global__ __launch_bounds__(256) void prep_all(
    const float* __restrict__ xp, const float* __restrict__ qp,
    const float* __restrict__ kp, const float* __restrict__ Wq,
    const float* __restrict__ Wk, const float* __restrict__ Wv,
    const float* __restrict__ Wp, const float* __restrict__ bp,
    u16* __restrict__ Xq, u16* __restrict__ Xk, u16* __restrict__ Xv,
    u16* __restrict__ Wb) {
  int bid = blockIdx.x;
  if (bid < PREP_BLKS) {
    int i4 = bid * 256 + threadIdx.x;
    int a4 = i4 % (LC / 4);
    f32x4 xx = ((const f32x4*)xp)[i4];
    f32x4 qq = ((const f32x4*)qp)[a4];
    f32x4 kk = ((const f32x4*)kp)[a4];
    ushort4v oq, ok, ov;
#pragma unroll
    for (int j = 0; j < 4; j++) {
      oq[j] = f2bf(xx[j] + qq[j]);
      ok[j] = f2bf(xx[j] + kk[j]);
      ov[j] = f2bf(xx[j]);
    }
    ((ushort4v*)Xq)[i4] = oq;
    ((ushort4v*)Xk)[i4] = ok;
    ((ushort4v*)Xv)[i4] = ov;
  } else {
    int i4 = (bid - PREP_BLKS) * 256 + threadIdx.x;
    if (i4 >= CONV_N4) return;
    int sel = i4 / (WSZ / 4);
    int off = i4 - sel * (WSZ / 4);
    const float* src = sel == 0 ? Wq : sel == 1 ? Wk : sel == 2 ? Wv
                     : sel == 3 ? Wp : bp;
    f32x4 v = ((const f32x4*)src)[off];
    ushort4v o;
#pragma unroll
    for (int j = 0; j < 4; j++) o[j] = f2bf(v[j]);
    ((ushort4v*)Wb)[i4] = o;
  }
}

// ---- 128x128 (K=768) bf16 GEMM core: C = A · Wᵀ ----
static __device__ __forceinline__ void gemm_core(
    const u16* __restrict__ Ab, const u16* __restrict__ Wb,
    short* As, short* Bs, f32x4 acc[4][4]) {
  const int t = threadIdx.x;
  const int lane = t & 63, w = t >> 6, quad = lane >> 4, l16 = lane & 15;
  const int wm = (w >> 1) * 64, wn = (w & 1) * 64;
  const int row4 = t >> 2, chunk = (t & 3) * 8;
  for (int k0 = 0; k0 < CDIM; k0 += 32) {
    const u16* ga = Ab + row4 * CDIM + k0 + chunk;
    const u16* gb = Wb + row4 * CDIM + k0 + chunk;
    lds_load16(ga,             (char*)As + t * 16);
    lds_load16(ga + 64 * CDIM, (char*)As + 4096 + t * 16);
    lds_load16(gb,             (char*)Bs + t * 16);
    lds_load16(gb + 64 * CDIM, (char*)Bs + 4096 + t * 16);
    __syncthreads();
    short8 af[4], bw[4];
#pragma unroll
    for (int i = 0; i < 4; i++)
      af[i] = *(const short8*)(As + (wm + i * 16 + l16) * 32 + quad * 8);
#pragma unroll
    for (int j = 0; j < 4; j++)
      bw[j] = *(const short8*)(Bs + (wn + j * 16 + l16) * 32 + quad * 8);
#pragma unroll
    for (int i = 0; i < 4; i++)
#pragma unroll
      for (int j = 0; j < 4; j++)
        acc[i][j] = mfma16(af[i], bw[j], acc[i][j]);
    __syncthreads();
  }
}

// ---- QKV projections. z=0:Q (pre-scaled 0.125) z=1:K (B,H,L,D); z=2:V^T ----
__global__ __launch_bounds__(256) void gemm_qkv(
    const u16* __restrict__ Xq, const u16* __restrict__ Xk, const u16* __restrict__ Xv,
    const u16* __restrict__ Wq, const u16* __restrict__ Wk, const u16* __restrict__ Wv,
    u16* __restrict__ Q, u16* __restrict__ K, u16* __restrict__ Vt) {
  __shared__ __align__(16) short S[128 * EST];
  short* As = S;
  short* Bs = S + 4096;
  const int z = blockIdx.z;
  const int m0 = blockIdx.y * 128, n0 = blockIdx.x * 128;
  const u16* A = (z == 0 ? Xq : z == 1 ? Xk : Xv) + m0 * CDIM;
  const u16* W = (z == 0 ? Wq : z == 1 ? Wk : Wv) + n0 * CDIM;
  f32x4 acc[4][4];
#pragma unroll
  for (int i = 0; i < 4; i++)
#pragma unroll
    for (int j = 0; j < 4; j++) acc[i][j] = 0.f;
  gemm_core(A, W, As, Bs, acc);

  const int t = threadIdx.x, lane = t & 63, w = t >> 6;
  const int quad = lane >> 4, l16 = lane & 15;
  const int wm = (w >> 1) * 64, wn = (w & 1) * 64;
  const float qs = (z == 0) ? 0.125f : 1.0f;

#pragma unroll
  for (int i = 0; i < 4; i++)
#pragma unroll
    for (int j = 0; j < 4; j++)
#pragma unroll
      for (int r = 0; r < 4; r++) {
        int mr = wm + i * 16 + quad * 4 + r;
        int nc = wn + j * 16 + l16;
        if (z < 2) S[mr * EST + nc] = (short)f2bf(acc[i][j][r] * qs);
        else       S[nc * EST + mr] = (short)f2bf(acc[i][j][r]);
      }
  __syncthreads();

  const int row = t >> 3, ch = t & 7;
  const int b = m0 >> 10, lbase = m0 & 1023;
  if (z < 2) {
    u16* O = (z == 0 ? Q : K);
#pragma unroll
    for (int cp = 0; cp < 2; cp++) {
      int h = (n0 >> 6) + cp;
#pragma unroll
      for (int rp = 0; rp < 4; rp++) {
        int mr = row + rp * 32;
        short8 v = *(const short8*)(S + mr * EST + cp * 64 + ch * 8);
        *(short8*)(O + ((((b * NH + h) << 10) + lbase + mr) * HD) + ch * 8) = v;
      }
    }
  } else {
#pragma unroll
    for (int rp = 0; rp < 4; rp++) {
      int rn = row + rp * 32;
      int h = (n0 + rn) >> 6, d = (n0 + rn) & 63;
#pragma unroll
      for (int cp = 0; cp < 2; cp++) {
        short8 v = *(const short8*)(S + rn * EST + cp * 64 + ch * 8);
        *(short8*)(Vt + ((b * NH + h) * HD + d) * SEQ + lbase + cp * 64 + ch * 8) = v;
      }
    }
  }
}

// ---- flash attention: barrier-free k-loop, direct-global K/V fragments ----
// QK^T B-frag = K[key][d0..d7] contiguous in (L,D); PV B-frag = Vt[d][key0..7]
// contiguous in (D,L). Only the P C->A transform touches LDS (per-wave region,
// same-wave lgkmcnt ordering, no barriers). Single-set register prefetch:
// each fragment set is reloaded for tile kt+1 right after tile kt consumes it.
__global__ __launch_bounds__(256) void attn(
    const u16* __restrict__ Q, const u16* __restrict__ K, const u16* __restrict__ Vt,
    const float* __restrict__ pos, u16* __restrict__ O) {
  __shared__ __align__(16) short Ps[4 * 16 * LST];
  const int t = threadIdx.x, lane = t & 63, w = t >> 6;
  const int quad = lane >> 4, l16 = lane & 15;
  const int qt = blockIdx.x, bh = blockIdx.y;
  const int b = bh / NH, h = bh % NH;
  const int q0 = qt * 64 + w * 16;

  const u16* Kg = K + bh * SEQ * HD;
  const u16* Vg = Vt + bh * HD * SEQ;
  const float* Pg = pos + (size_t)(h * SEQ + q0) * SEQ;
  short* Pw = Ps + w * 16 * LST;

  const u16* Qg = Q + (bh * SEQ + q0) * HD;
  const short8 qa0 = *(const short8*)(Qg + l16 * HD + quad * 8);
  const short8 qa1 = *(const short8*)(Qg + l16 * HD + 32 + quad * 8);

  f32x4 o[4];
#pragma unroll
  for (int j = 0; j < 4; j++) o[j] = 0.f;
  float lrow[4] = {0.f, 0.f, 0.f, 0.f};

  // fragment registers (single sets; prefetch overwrites after consumption)
  short8 kf0[4], kf1[4], vf0[4], vf1[4];
  float pf[16];
#pragma unroll
  for (int j = 0; j < 4; j++) {
    kf0[j] = *(const short8*)(Kg + (j * 16 + l16) * HD + quad * 8);
    kf1[j] = *(const short8*)(Kg + (j * 16 + l16) * HD + 32 + quad * 8);
    vf0[j] = *(const short8*)(Vg + (j * 16 + l16) * SEQ + quad * 8);
    vf1[j] = *(const short8*)(Vg + (j * 16 + l16) * SEQ + 32 + quad * 8);
  }
#pragma unroll
  for (int j = 0; j < 4; j++)
#pragma unroll
    for (int r = 0; r < 4; r++)
      pf[j * 4 + r] = Pg[(quad * 4 + r) * SEQ + j * 16 + l16] * L2E;

#pragma unroll 1
  for (int kt = 0; kt < 16; kt++) {
    const int kn = (kt < 15 ? kt + 1 : 15) * 64;

    // S = Q·Kᵀ (Q pre-scaled by 0.125); then refill K-frags for kt+1
    f32x4 s[4];
#pragma unroll
    for (int j = 0; j < 4; j++) {
      f32x4 zz = 0.f;
      s[j] = mfma16(qa1, kf1[j], mfma16(qa0, kf0[j], zz));
    }
#pragma unroll
    for (int j = 0; j < 4; j++) {
      kf0[j] = *(const short8*)(Kg + (kn + j * 16 + l16) * HD + quad * 8);
      kf1[j] = *(const short8*)(Kg + (kn + j * 16 + l16) * HD + 32 + quad * 8);
    }

    // P = exp2(s·log2e + pos·log2e) — no-max softmax (validated R6/R8);
    // lrow sums the same bf16-truncated values stored to LDS (bias cancels).
#pragma unroll
    for (int j = 0; j < 4; j++)
#pragma unroll
      for (int r = 0; r < 4; r++) {
        float e = __builtin_amdgcn_exp2f(fmaf(s[j][r], L2E, pf[j * 4 + r]));
        unsigned bits = __float_as_uint(e);
        Pw[(quad * 4 + r) * LST + j * 16 + l16] = (short)(bits >> 16);
        lrow[r] += __uint_as_float(bits & 0xFFFF0000u);
      }
    // refill pos for kt+1
#pragma unroll
    for (int j = 0; j < 4; j++)
#pragma unroll
      for (int r = 0; r < 4; r++)
        pf[j * 4 + r] = Pg[(quad * 4 + r) * SEQ + kn + j * 16 + l16] * L2E;

    // P C-layout -> A-layout via per-wave LDS (same-wave ordering, no barrier)
    short8 pa0 = *(const short8*)(Pw + l16 * LST + quad * 8);
    short8 pa1 = *(const short8*)(Pw + l16 * LST + 32 + quad * 8);
#pragma unroll
    for (int j = 0; j < 4; j++)
      o[j] = mfma16(pa1, vf1[j], mfma16(pa0, vf0[j], o[j]));
    // refill V-frags for kt+1
#pragma unroll
    for (int j = 0; j < 4; j++) {
      vf0[j] = *(const short8*)(Vg + (j * 16 + l16) * SEQ + kn + quad * 8);
      vf1[j] = *(const short8*)(Vg + (j * 16 + l16) * SEQ + kn + 32 + quad * 8);
    }
  }

  // end-of-kernel row-sum across the 16 lanes of each quad-row group
#pragma unroll
  for (int off = 1; off < 16; off <<= 1)
#pragma unroll
    for (int r = 0; r < 4; r++) lrow[r] += __shfl_xor(lrow[r], off);

  u16* Og = O + (b * SEQ + q0) * CDIM + h * HD;
  float inv[4];
#pragma unroll
  for (int r = 0; r < 4; r++) inv[r] = 1.0f / lrow[r];
#pragma unroll
  for (int j = 0; j < 4; j++)
#pragma unroll
    for (int r = 0; r < 4; r++)
      Og[(quad * 4 + r) * CDIM + j * 16 + l16] = f2bf(o[j][r] * inv[r]);
}

// ---- output projection + bias, FP32 output ----
__global__ __launch_bounds__(256) void gemm_proj(
    const u16* __restrict__ Oin, const u16* __restrict__ Wp,
    const u16* __restrict__ bp, float* __restrict__ out) {
  __shared__ __align__(16) short As[128 * 32], Bs[128 * 32];
  const int m0 = blockIdx.y * 128, n0 = blockIdx.x * 128;
  f32x4 acc[4][4];
#pragma unroll
  for (int i = 0; i < 4; i++)
#pragma unroll
    for (int j = 0; j < 4; j++) acc[i][j] = 0.f;
  gemm_core(Oin + m0 * CDIM, Wp + n0 * CDIM, As, Bs, acc);

  const int t = threadIdx.x, lane = t & 63, w = t >> 6;
  const int quad = lane >> 4, l16 = lane & 15;
  const int wm = (w >> 1) * 64, wn = (w & 1) * 64;
#pragma unroll
  for (int i = 0; i < 4; i++) {
    int mrow = m0 + wm + i * 16 + quad * 4;
#pragma unroll
    for (int j = 0; j < 4; j++) {
      int n = n0 + wn + j * 16 + l16;
      float bias = bf2f(bp[n]);
#pragma unroll
      for (int r = 0; r < 4; r++)
        out[(mrow + r) * CDIM + n] = acc[i][j][r] + bias;
    }
  }
}

extern "C" void kernel_launch(void* const* d_in, const int* in_sizes, int n_in,
                              void* d_out, int out_size, void* d_ws, size_t ws_size,
                              hipStream_t stream) {
  (void)in_sizes; (void)n_in; (void)out_size;
  const size_t OFF_XQ = 0, OFF_XK = (size_t)MC, OFF_XV = 2ull * MC,
               OFF_Q = 3ull * MC, OFF_K = 4ull * MC, OFF_VT = 5ull * MC,
               OFF_W = 6ull * MC, TOT = OFF_W + 4ull * WSZ + 1024;
  const size_t NEED = 2 * TOT;
  if (ws_size < NEED) return;

  u16* ws = (u16*)d_ws;
  u16 *Xq = ws + OFF_XQ, *Xk = ws + OFF_XK, *Xv = ws + OFF_XV;
  u16 *Qb = ws + OFF_Q, *Kb = ws + OFF_K, *Vt = ws + OFF_VT;
  u16 *Wb = ws + OFF_W;
  u16 *Wqb = Wb, *Wkb = Wb + WSZ, *Wvb = Wb + 2ull * WSZ,
      *Wpb = Wb + 3ull * WSZ, *bpb = Wb + 4ull * WSZ;
  u16* Ob = Xq;

  prep_all<<<PREP_BLKS + CONV_BLKS, 256, 0, stream>>>(
      (const float*)d_in[0], (const float*)d_in[1], (const float*)d_in[2],
      (const float*)d_in[4], (const float*)d_in[5], (const float*)d_in[6],
      (const float*)d_in[7], (const float*)d_in[8], Xq, Xk, Xv, Wb);
  gemm_qkv<<<dim3(6, 32, 3), 256, 0, stream>>>(Xq, Xk, Xv, Wqb, Wkb, Wvb,
                                               Qb, Kb, Vt);
  attn<<<dim3(16, 48), 256, 0, stream>>>(Qb, Kb, Vt, (const float*)d_in[3], Ob);
  gemm_proj<<<dim3(6, 32), 256, 0, stream>>>(Ob, Wpb, bpb, (float*)d_out);
}

// Round 10
// 218.164 us; speedup vs baseline: 1.2320x; 1.2320x over previous
//
#include <hip/hip_runtime.h>
#include <stdint.h>

#define NH 12
#define HD 64
#define NB 4
#define SEQ 1024
#define CDIM 768
#define MTOT (NB*SEQ)
#define MC   (MTOT*CDIM)      /* 3145728 */
#define LC   (SEQ*CDIM)       /* 786432  */
#define WSZ  (CDIM*CDIM)      /* 589824  */
#define LST  104              /* attn LDS row stride (shorts) */
#define EST  136              /* epilogue LDS row stride (shorts) */
#define L2E  1.44269504f

typedef __attribute__((ext_vector_type(4))) float f32x4;
typedef __attribute__((ext_vector_type(8))) __bf16 bf16x8;
typedef __attribute__((ext_vector_type(8))) short short8;
typedef __attribute__((ext_vector_type(4))) unsigned short ushort4v;
typedef unsigned short u16;

static __device__ __forceinline__ f32x4 mfma16(short8 a, short8 b, f32x4 c) {
  return __builtin_amdgcn_mfma_f32_16x16x32_bf16(
      __builtin_bit_cast(bf16x8, a), __builtin_bit_cast(bf16x8, b), c, 0, 0, 0);
}
static __device__ __forceinline__ u16 f2bf(float f) {
  unsigned u = __float_as_uint(f);
  u += 0x7FFFu + ((u >> 16) & 1u);
  return (u16)(u >> 16);
}
static __device__ __forceinline__ float bf2f(u16 h) {
  return __uint_as_float(((unsigned)h) << 16);
}
static __device__ __forceinline__ void lds_load16(const void* g, void* l) {
  __builtin_amdgcn_global_load_lds(
      (const __attribute__((address_space(1))) void*)g,
      (__attribute__((address_space(3))) void*)l, 16, 0, 0);
}
// barrier WITHOUT the compiler's vmcnt(0) drain: wait LDS ops only.
static __device__ __forceinline__ void barrier_lgkm() {
  __builtin_amdgcn_s_waitcnt(0xC07F);   // lgkmcnt(0), vmcnt/expcnt don't-care
  __builtin_amdgcn_s_barrier();
}

// ---- fused prep: Xq/Xk/Xv bf16 tokens + all weights/bias -> bf16 ----
#define PREP_BLKS (MC / 4 / 256)
#define CONV_N4   ((4 * WSZ + CDIM) / 4)
#define CONV_BLKS ((CONV_N4 + 255) / 256)
__global__ __launch_bounds__(256) void prep_all(
    const float* __restrict__ xp, const float* __restrict__ qp,
    const float* __restrict__ kp, const float* __restrict__ Wq,
    const float* __restrict__ Wk, const float* __restrict__ Wv,
    const float* __restrict__ Wp, const float* __restrict__ bp,
    u16* __restrict__ Xq, u16* __restrict__ Xk, u16* __restrict__ Xv,
    u16* __restrict__ Wb) {
  int bid = blockIdx.x;
  if (bid < PREP_BLKS) {
    int i4 = bid * 256 + threadIdx.x;
    int a4 = i4 % (LC / 4);
    f32x4 xx = ((const f32x4*)xp)[i4];
    f32x4 qq = ((const f32x4*)qp)[a4];
    f32x4 kk = ((const f32x4*)kp)[a4];
    ushort4v oq, ok, ov;
#pragma unroll
    for (int j = 0; j < 4; j++) {
      oq[j] = f2bf(xx[j] + qq[j]);
      ok[j] = f2bf(xx[j] + kk[j]);
      ov[j] = f2bf(xx[j]);
    }
    ((ushort4v*)Xq)[i4] = oq;
    ((ushort4v*)Xk)[i4] = ok;
    ((ushort4v*)Xv)[i4] = ov;
  } else {
    int i4 = (bid - PREP_BLKS) * 256 + threadIdx.x;
    if (i4 >= CONV_N4) return;
    int sel = i4 / (WSZ / 4);
    int off = i4 - sel * (WSZ / 4);
    const float* src = sel == 0 ? Wq : sel == 1 ? Wk : sel == 2 ? Wv
                     : sel == 3 ? Wp : bp;
    f32x4 v = ((const f32x4*)src)[off];
    ushort4v o;
#pragma unroll
    for (int j = 0; j < 4; j++) o[j] = f2bf(v[j]);
    ((ushort4v*)Wb)[i4] = o;
  }
}

// ---- 128x128 (K=768) bf16 GEMM core, BK=64 as two interleaved BK=32 halves
// (keeps global_load_lds contiguity + m97 LDS banking; halves barrier count).
static __device__ __forceinline__ void gemm_core(
    const u16* __restrict__ Ab, const u16* __restrict__ Wb,
    short* As, short* Bs, f32x4 acc[4][4]) {
  const int t = threadIdx.x;
  const int lane = t & 63, w = t >> 6, quad = lane >> 4, l16 = lane & 15;
  const int wm = (w >> 1) * 64, wn = (w & 1) * 64;
  const int row4 = t >> 2, chunk = (t & 3) * 8;
  for (int k0 = 0; k0 < CDIM; k0 += 64) {
#pragma unroll
    for (int hh = 0; hh < 2; hh++) {
      const u16* ga = Ab + row4 * CDIM + k0 + hh * 32 + chunk;
      const u16* gb = Wb + row4 * CDIM + k0 + hh * 32 + chunk;
      lds_load16(ga,             (char*)As + hh * 8192 + t * 16);
      lds_load16(ga + 64 * CDIM, (char*)As + hh * 8192 + 4096 + t * 16);
      lds_load16(gb,             (char*)Bs + hh * 8192 + t * 16);
      lds_load16(gb + 64 * CDIM, (char*)Bs + hh * 8192 + 4096 + t * 16);
    }
    __syncthreads();
#pragma unroll
    for (int hh = 0; hh < 2; hh++) {
      const short* Ah = As + hh * 4096;
      const short* Bh = Bs + hh * 4096;
      short8 af[4], bw[4];
#pragma unroll
      for (int i = 0; i < 4; i++)
        af[i] = *(const short8*)(Ah + (wm + i * 16 + l16) * 32 + quad * 8);
#pragma unroll
      for (int j = 0; j < 4; j++)
        bw[j] = *(const short8*)(Bh + (wn + j * 16 + l16) * 32 + quad * 8);
#pragma unroll
      for (int i = 0; i < 4; i++)
#pragma unroll
        for (int j = 0; j < 4; j++)
          acc[i][j] = mfma16(af[i], bw[j], acc[i][j]);
    }
    __syncthreads();
  }
}

// ---- QKV projections. z=0:Q (pre-scaled 0.125) z=1:K (B,H,L,D); z=2:V^T ----
__global__ __launch_bounds__(256) void gemm_qkv(
    const u16* __restrict__ Xq, const u16* __restrict__ Xk, const u16* __restrict__ Xv,
    const u16* __restrict__ Wq, const u16* __restrict__ Wk, const u16* __restrict__ Wv,
    u16* __restrict__ Q, u16* __restrict__ K, u16* __restrict__ Vt) {
  __shared__ __align__(16) short S[128 * EST];   // 34816 B; As/Bs carved (16K ea)
  short* As = S;
  short* Bs = S + 8192;
  const int z = blockIdx.z;
  const int m0 = blockIdx.y * 128, n0 = blockIdx.x * 128;
  const u16* A = (z == 0 ? Xq : z == 1 ? Xk : Xv) + m0 * CDIM;
  const u16* W = (z == 0 ? Wq : z == 1 ? Wk : Wv) + n0 * CDIM;
  f32x4 acc[4][4];
#pragma unroll
  for (int i = 0; i < 4; i++)
#pragma unroll
    for (int j = 0; j < 4; j++) acc[i][j] = 0.f;
  gemm_core(A, W, As, Bs, acc);

  const int t = threadIdx.x, lane = t & 63, w = t >> 6;
  const int quad = lane >> 4, l16 = lane & 15;
  const int wm = (w >> 1) * 64, wn = (w & 1) * 64;
  const float qs = (z == 0) ? 0.125f : 1.0f;

#pragma unroll
  for (int i = 0; i < 4; i++)
#pragma unroll
    for (int j = 0; j < 4; j++)
#pragma unroll
      for (int r = 0; r < 4; r++) {
        int mr = wm + i * 16 + quad * 4 + r;
        int nc = wn + j * 16 + l16;
        if (z < 2) S[mr * EST + nc] = (short)f2bf(acc[i][j][r] * qs);
        else       S[nc * EST + mr] = (short)f2bf(acc[i][j][r]);
      }
  __syncthreads();

  const int row = t >> 3, ch = t & 7;
  const int b = m0 >> 10, lbase = m0 & 1023;
  if (z < 2) {
    u16* O = (z == 0 ? Q : K);
#pragma unroll
    for (int cp = 0; cp < 2; cp++) {
      int h = (n0 >> 6) + cp;
#pragma unroll
      for (int rp = 0; rp < 4; rp++) {
        int mr = row + rp * 32;
        short8 v = *(const short8*)(S + mr * EST + cp * 64 + ch * 8);
        *(short8*)(O + ((((b * NH + h) << 10) + lbase + mr) * HD) + ch * 8) = v;
      }
    }
  } else {
#pragma unroll
    for (int rp = 0; rp < 4; rp++) {
      int rn = row + rp * 32;
      int h = (n0 + rn) >> 6, d = (n0 + rn) & 63;
#pragma unroll
      for (int cp = 0; cp < 2; cp++) {
        short8 v = *(const short8*)(S + rn * EST + cp * 64 + ch * 8);
        *(short8*)(Vt + ((b * NH + h) * HD + d) * SEQ + lbase + cp * 64 + ch * 8) = v;
      }
    }
  }
}

// ---- flash attention (R8 verbatim: pipelined k-loop + light exp2 softmax) ----
struct AttnCtx {
  const u16 *Kg, *Vg; const float* Pg;
  short *Ks, *Vs, *Pw;
  int sr, sc, quad, l16;
  short8 qa0, qa1;
  short8 kr0, kr1, vr0, vr1;
  f32x4 o[4];
  float lrow[4];
};

static __device__ __forceinline__ void attn_tile(
    AttnCtx& c, int kt, float (&pin)[16], float (&pout)[16], bool pre) {
  barrier_lgkm();
  *(short8*)(c.Ks + c.sr * LST + c.sc)        = c.kr0;
  *(short8*)(c.Ks + (c.sr + 32) * LST + c.sc) = c.kr1;
  *(short8*)(c.Vs + c.sr * LST + c.sc)        = c.vr0;
  *(short8*)(c.Vs + (c.sr + 32) * LST + c.sc) = c.vr1;
  if (pre) {
    const int k1 = (kt + 1) * 64;
    const u16* kg = c.Kg + k1 * HD;
    c.kr0 = *(const short8*)(kg + c.sr * HD + c.sc);
    c.kr1 = *(const short8*)(kg + (c.sr + 32) * HD + c.sc);
    const u16* vg = c.Vg + k1;
    c.vr0 = *(const short8*)(vg + c.sr * SEQ + c.sc);
    c.vr1 = *(const short8*)(vg + (c.sr + 32) * SEQ + c.sc);
    const float* pg = c.Pg + k1;
#pragma unroll
    for (int j = 0; j < 4; j++)
#pragma unroll
      for (int r = 0; r < 4; r++)
        pout[j * 4 + r] = pg[(c.quad * 4 + r) * SEQ + j * 16 + c.l16] * L2E;
  }
  barrier_lgkm();

  const int quad = c.quad, l16 = c.l16;
  f32x4 s[4];
#pragma unroll
  for (int j = 0; j < 4; j++) {
    short8 kb0 = *(const short8*)(c.Ks + (j * 16 + l16) * LST + quad * 8);
    short8 kb1 = *(const short8*)(c.Ks + (j * 16 + l16) * LST + 32 + quad * 8);
    f32x4 zz = 0.f;
    s[j] = mfma16(c.qa1, kb1, mfma16(c.qa0, kb0, zz));
  }

  // P = exp2(s·log2e + pos·log2e) — no-max softmax (validated R6/R8); lrow
  // accumulates the SAME bf16-truncated values stored to LDS (bias cancels).
#pragma unroll
  for (int j = 0; j < 4; j++)
#pragma unroll
    for (int r = 0; r < 4; r++) {
      float e = __builtin_amdgcn_exp2f(fmaf(s[j][r], L2E, pin[j * 4 + r]));
      unsigned bits = __float_as_uint(e);
      c.Pw[(quad * 4 + r) * LST + j * 16 + l16] = (short)(bits >> 16);
      c.lrow[r] += __uint_as_float(bits & 0xFFFF0000u);
    }

  short8 pa0 = *(const short8*)(c.Pw + l16 * LST + quad * 8);
  short8 pa1 = *(const short8*)(c.Pw + l16 * LST + 32 + quad * 8);
#pragma unroll
  for (int j = 0; j < 4; j++) {
    short8 vb0 = *(const short8*)(c.Vs + (j * 16 + l16) * LST + quad * 8);
    short8 vb1 = *(const short8*)(c.Vs + (j * 16 + l16) * LST + 32 + quad * 8);
    c.o[j] = mfma16(pa1, vb1, mfma16(pa0, vb0, c.o[j]));
  }
}

__global__ __launch_bounds__(256) void attn(
    const u16* __restrict__ Q, const u16* __restrict__ K, const u16* __restrict__ Vt,
    const float* __restrict__ pos, u16* __restrict__ O) {
  __shared__ __align__(16) short Ks[64 * LST], Vs[64 * LST], Ps[64 * LST];
  const int t = threadIdx.x, lane = t & 63, w = t >> 6;
  const int qt = blockIdx.x, bh = blockIdx.y;
  const int b = bh / NH, h = bh % NH;
  const int q0 = qt * 64 + w * 16;

  AttnCtx c;
  c.quad = lane >> 4; c.l16 = lane & 15;
  c.sr = t >> 3; c.sc = (t & 7) * 8;
  c.Ks = Ks; c.Vs = Vs; c.Pw = Ps + w * 16 * LST;
  c.Kg = K + bh * SEQ * HD;
  c.Vg = Vt + bh * HD * SEQ;
  c.Pg = pos + (size_t)(h * SEQ + q0) * SEQ;

  const u16* Qg = Q + (bh * SEQ + q0) * HD;
  c.qa0 = *(const short8*)(Qg + c.l16 * HD + c.quad * 8);
  c.qa1 = *(const short8*)(Qg + c.l16 * HD + 32 + c.quad * 8);

#pragma unroll
  for (int j = 0; j < 4; j++) c.o[j] = 0.f;
#pragma unroll
  for (int r = 0; r < 4; r++) c.lrow[r] = 0.f;

  c.kr0 = *(const short8*)(c.Kg + c.sr * HD + c.sc);
  c.kr1 = *(const short8*)(c.Kg + (c.sr + 32) * HD + c.sc);
  c.vr0 = *(const short8*)(c.Vg + c.sr * SEQ + c.sc);
  c.vr1 = *(const short8*)(c.Vg + (c.sr + 32) * SEQ + c.sc);
  float pfA[16], pfB[16];
#pragma unroll
  for (int j = 0; j < 4; j++)
#pragma unroll
    for (int r = 0; r < 4; r++)
      pfA[j * 4 + r] = c.Pg[(c.quad * 4 + r) * SEQ + j * 16 + c.l16] * L2E;

#pragma unroll 1
  for (int kt = 0; kt < 16; kt += 2) {
    attn_tile(c, kt, pfA, pfB, true);
    attn_tile(c, kt + 1, pfB, pfA, kt + 1 < 15);
  }

#pragma unroll
  for (int off = 1; off < 16; off <<= 1)
#pragma unroll
    for (int r = 0; r < 4; r++) c.lrow[r] += __shfl_xor(c.lrow[r], off);

  u16* Og = O + (b * SEQ + q0) * CDIM + h * HD;
  float inv[4];
#pragma unroll
  for (int r = 0; r < 4; r++) inv[r] = 1.0f / c.lrow[r];
#pragma unroll
  for (int j = 0; j < 4; j++)
#pragma unroll
    for (int r = 0; r < 4; r++)
      Og[(c.quad * 4 + r) * CDIM + j * 16 + c.l16] = f2bf(c.o[j][r] * inv[r]);
}

// ---- output projection + bias, FP32 output ----
__global__ __launch_bounds__(256) void gemm_proj(
    const u16* __restrict__ Oin, const u16* __restrict__ Wp,
    const u16* __restrict__ bp, float* __restrict__ out) {
  __shared__ __align__(16) short As[8192], Bs[8192];
  const int m0 = blockIdx.y * 128, n0 = blockIdx.x * 128;
  f32x4 acc[4][4];
#pragma unroll
  for (int i = 0; i < 4; i++)
#pragma unroll
    for (int j = 0; j < 4; j++) acc[i][j] = 0.f;
  gemm_core(Oin + m0 * CDIM, Wp + n0 * CDIM, As, Bs, acc);

  const int t = threadIdx.x, lane = t & 63, w = t >> 6;
  const int quad = lane >> 4, l16 = lane & 15;
  const int wm = (w >> 1) * 64, wn = (w & 1) * 64;
#pragma unroll
  for (int i = 0; i < 4; i++) {
    int mrow = m0 + wm + i * 16 + quad * 4;
#pragma unroll
    for (int j = 0; j < 4; j++) {
      int n = n0 + wn + j * 16 + l16;
      float bias = bf2f(bp[n]);
#pragma unroll
      for (int r = 0; r < 4; r++)
        out[(mrow + r) * CDIM + n] = acc[i][j][r] + bias;
    }
  }
}

extern "C" void kernel_launch(void* const* d_in, const int* in_sizes, int n_in,
                              void* d_out, int out_size, void* d_ws, size_t ws_size,
                              hipStream_t stream) {
  (void)in_sizes; (void)n_in; (void)out_size;
  const size_t OFF_XQ = 0, OFF_XK = (size_t)MC, OFF_XV = 2ull * MC,
               OFF_Q = 3ull * MC, OFF_K = 4ull * MC, OFF_VT = 5ull * MC,
               OFF_W = 6ull * MC, TOT = OFF_W + 4ull * WSZ + 1024;
  const size_t NEED = 2 * TOT;
  if (ws_size < NEED) return;

  u16* ws = (u16*)d_ws;
  u16 *Xq = ws + OFF_XQ, *Xk = ws + OFF_XK, *Xv = ws + OFF_XV;
  u16 *Qb = ws + OFF_Q, *Kb = ws + OFF_K, *Vt = ws + OFF_VT;
  u16 *Wb = ws + OFF_W;
  u16 *Wqb = Wb, *Wkb = Wb + WSZ, *Wvb = Wb + 2ull * WSZ,
      *Wpb = Wb + 3ull * WSZ, *bpb = Wb + 4ull * WSZ;
  u16* Ob = Xq;

  prep_all<<<PREP_BLKS + CONV_BLKS, 256, 0, stream>>>(
      (const float*)d_in[0], (const float*)d_in[1], (const float*)d_in[2],
      (const float*)d_in[4], (const float*)d_in[5], (const float*)d_in[6],
      (const float*)d_in[7], (const float*)d_in[8], Xq, Xk, Xv, Wb);
  gemm_qkv<<<dim3(6, 32, 3), 256, 0, stream>>>(Xq, Xk, Xv, Wqb, Wkb, Wvb,
                                               Qb, Kb, Vt);
  attn<<<dim3(16, 48), 256, 0, stream>>>(Qb, Kb, Vt, (const float*)d_in[3], Ob);
  gemm_proj<<<dim3(6, 32), 256, 0, stream>>>(Ob, Wpb, bpb, (float*)d_out);
}